// Round 12
// baseline (184.725 us; speedup 1.0000x reference)
//
#include <hip/hip_runtime.h>
#include <cstdint>
#include <cstddef>

#define HH 256
#define WW 256
#define CIN 16
#define COUT 32
#define NB 2
#define TW 32
#define TH 8
#define NPIX (TW*TH)            // 256 pixels/block
#define HALO 5
#define LR_ROWS (TH + 2*HALO)   // 18
#define LR_COLS (TW + 2*HALO)   // 42
#define NCELL (LR_ROWS*LR_COLS) // 756
#define HW (HH*WW)

typedef float f32x2 __attribute__((ext_vector_type(2)));
__device__ __forceinline__ f32x2 splat2(float v) { return f32x2{v, v}; }

// ---------------- compile-time offset tables ----------------
struct alignas(16) Tables {
  int16_t coff[256];     // (g*16+n) -> cell offset dx*LR_COLS+dy (phase 2)
  int16_t hpc[2][96];    // per-half dedup'd distinct-pair cell offsets
  uint8_t hgmap[256];    // (g*16+n) -> index within half (g>>3)'s array
  int     hnp[2];        // distinct-pair count per half
};

// numpy round-half-to-even for non-negative v (only .0/.5 cases occur)
constexpr int rhe(double v) {
  int f = (int)v;
  double fr = v - (double)f;
  if (fr > 0.5) return f + 1;
  if (fr < 0.5) return f;
  return (f & 1) ? f + 1 : f;
}

constexpr Tables make_tables() {
  Tables t{};
  int dxa[256] = {}, dya[256] = {};
  for (int g = 0; g < 16; ++g) {
    int hp = (g >> 2) + 2;   // rb + gh
    int wp = (g & 3) + 2;    // rb + gw
    int TD[5] = {}, LRr[3] = {};
    for (int j = 0; j < 5; ++j) TD[j] = rhe(j * wp / 2.0) - wp;
    for (int j = 0; j < 3; ++j) LRr[j] = rhe((j + 1) * hp / 2.0) - hp;
    int dxs[16] = {}, dys[16] = {};
    for (int j = 0; j < 5; ++j) { dxs[j]      = -hp;    dys[j]      = TD[j]; }
    for (int j = 0; j < 3; ++j) { dxs[5 + j]  = LRr[j]; dys[5 + j]  =  wp;   }
    for (int j = 0; j < 5; ++j) { dxs[8 + j]  =  hp;    dys[8 + j]  = TD[j]; }
    for (int j = 0; j < 3; ++j) { dxs[13 + j] = LRr[j]; dys[13 + j] = -wp;   }
    for (int n = 0; n < 16; ++n) {
      dxa[g * 16 + n] = dxs[n]; dya[g * 16 + n] = dys[n];
      t.coff[g * 16 + n] = (int16_t)(dxs[n] * LR_COLS + dys[n]);
    }
  }
  // per-half dedup: half z covers groups [8z, 8z+8)  (hp-split)
  for (int z = 0; z < 2; ++z) {
    t.hnp[z] = 0;
    for (int g = z * 8; g < z * 8 + 8; ++g) {
      for (int n = 0; n < 16; ++n) {
        int co = dxa[g * 16 + n] * LR_COLS + dya[g * 16 + n];
        int d = -1;
        for (int k = 0; k < t.hnp[z]; ++k)
          if ((int)t.hpc[z][k] == co) { d = k; break; }
        if (d < 0) { d = t.hnp[z]; t.hnp[z]++; t.hpc[z][d] = (int16_t)co; }
        t.hgmap[g * 16 + n] = (uint8_t)d;
      }
    }
  }
  return t;
}

constexpr Tables CT = make_tables();
static_assert(CT.hnp[0] <= 96 && CT.hnp[1] <= 96, "half table overflow");
static_assert(CT.hnp[0] % 4 == 0 && CT.hnp[1] % 4 == 0, "quad remainder");
__device__ const Tables DT = make_tables();   // for runtime-indexed phase-2 reads

// ------- exact transcription of numpy's SIMD f32 exp, 2-wide packed -------
__device__ __forceinline__ f32x2 numpy_expf2(f32x2 v) {
#pragma clang fp contract(off)
  const f32x2 MAGIC = splat2(12582912.0f);         // 1.5 * 2^23
  f32x2 q = __builtin_elementwise_fma(v, splat2(1.442695040888963407359e+00f), MAGIC);
  q = q - MAGIC;                                   // rint(v*log2e), single rounding
  f32x2 r = __builtin_elementwise_fma(q, splat2(-6.93145752e-1f), v);
  r = __builtin_elementwise_fma(q, splat2(-1.42860677e-6f), r);
  f32x2 num = __builtin_elementwise_fma(splat2(5.082762527590693718096e-04f), r,
                                        splat2(6.757896990527504603057e-03f));
  num = __builtin_elementwise_fma(num, r, splat2(5.114512081637298353406e-02f));
  num = __builtin_elementwise_fma(num, r, splat2(2.473615434895520810817e-01f));
  num = __builtin_elementwise_fma(num, r, splat2(7.257664613233124478488e-01f));
  num = __builtin_elementwise_fma(num, r, splat2(9.999999999980870924916e-01f));
  f32x2 den = __builtin_elementwise_fma(splat2(2.159509375685829852307e-02f), r,
                                        splat2(-2.742335390411667452936e-01f));
  den = __builtin_elementwise_fma(den, r, splat2(1.0f));
  f32x2 res;
  res.x = ldexpf(num.x / den.x, (int)q.x);         // IEEE div + exact pow2 scale
  res.y = ldexpf(num.y / den.y, (int)q.y);
  return res;
}

// ---- phase 1 for one half: packed quad-batched pair sigmoids + 8 sims ----
template<int Z>
__device__ __forceinline__ void phase1_half(float* simr,
    const float4* xt4, int lbase, const f32x2* xcl)
{
#pragma clang fp contract(off)
  constexpr int HN = CT.hnp[Z];
  float myv[HN];
#pragma unroll
  for (int bb = 0; bb < HN / 4; ++bb) {
    float4 R[4][4];
#pragma unroll
    for (int j = 0; j < 4; ++j) {
      const int cell = lbase + (int)CT.hpc[Z][bb * 4 + j];   // compile-time offset
#pragma unroll
      for (int q = 0; q < 4; ++q) R[j][q] = xt4[q * NCELL + cell];
    }
    float mloc[4];
#pragma unroll
    for (int j = 0; j < 4; ++j) {
      // products rounded individually (v_pk_mul pairs 2 IEEE muls/slot)
      f32x2 pr[8];
#pragma unroll
      for (int q = 0; q < 4; ++q) {
        pr[2*q]   = f32x2{R[j][q].x, R[j][q].y} * xcl[2*q];
        pr[2*q+1] = f32x2{R[j][q].z, R[j][q].w} * xcl[2*q+1];
      }
      // sequential channel sum c=0..15 (numpy outer-axis reduce), unfused
      float s = pr[0].x;
      s += pr[0].y; s += pr[1].x; s += pr[1].y;
      s += pr[2].x; s += pr[2].y; s += pr[3].x; s += pr[3].y;
      s += pr[4].x; s += pr[4].y; s += pr[5].x; s += pr[5].y;
      s += pr[6].x; s += pr[6].y; s += pr[7].x; s += pr[7].y;
      mloc[j] = s / 16.0f;                   // exact (pow2)
    }
#pragma unroll
    for (int h = 0; h < 2; ++h) {
      f32x2 mv = { mloc[2*h], mloc[2*h+1] };
      f32x2 e2 = numpy_expf2(-mv);           // numpy's exact SIMD exp, per lane
      f32x2 d1 = splat2(1.0f) + e2;
      myv[bb*4 + 2*h]     = 1.0f / d1.x;     // IEEE f32 div
      myv[bb*4 + 2*h + 1] = 1.0f / d1.y;
    }
  }
  // numpy SSE2 pairwise tree per group (compile-time wiring into myv)
#pragma unroll
  for (int gg = 0; gg < 8; ++gg) {
    const int base = (Z * 8 + gg) * 16;
    float A0 = (myv[CT.hgmap[base + 0]]  + myv[CT.hgmap[base + 8]])
             + (myv[CT.hgmap[base + 4]]  + myv[CT.hgmap[base + 12]]);
    float A1 = (myv[CT.hgmap[base + 1]]  + myv[CT.hgmap[base + 9]])
             + (myv[CT.hgmap[base + 5]]  + myv[CT.hgmap[base + 13]]);
    float A2 = (myv[CT.hgmap[base + 2]]  + myv[CT.hgmap[base + 10]])
             + (myv[CT.hgmap[base + 6]]  + myv[CT.hgmap[base + 14]]);
    float A3 = (myv[CT.hgmap[base + 3]]  + myv[CT.hgmap[base + 11]])
             + (myv[CT.hgmap[base + 7]]  + myv[CT.hgmap[base + 15]]);
    float ssum = (A0 + A2) + (A1 + A3);
    simr[gg] = ssum / 16.0f;                 // exact (pow2)
  }
}

// ---------- weight transpose: w[o][c][n] -> wt2[n][o/2][c][2] ----------
__global__ void transpose_w(const float* __restrict__ w, float* __restrict__ wt2) {
  int i = blockIdx.x * 256 + threadIdx.x;
  if (i < COUT * CIN * 16) {
    int o = i >> 8, c = (i >> 4) & 15, n = i & 15;
    wt2[(((n * 16 + (o >> 1)) * 16 + c) << 1) + (o & 1)] = w[i];
  }
}

// ------------- fused main kernel: 2 threads/pixel, 512-thread block -------------
__global__ __launch_bounds__(512)
__attribute__((amdgpu_waves_per_eu(4, 4)))   // 2 blocks/CU x 8 waves -> 4 waves/EU; VGPR<=128
void adapkc_main(
    const float* __restrict__ x, const float* __restrict__ wt2,
    const float* __restrict__ bias, float* __restrict__ out)
{
#pragma clang fp contract(off)   // numpy never fuses mul+add; keep every rounding
  __shared__ float4 xt4[4 * NCELL];          // 48,384 B
  __shared__ float  sims_s[NPIX][17];        // 17,408 B (pad 17: odd stride, 2-way = free)

  const int tx = threadIdx.x, ty = threadIdx.y, tz = threadIdx.z;
  const int pix = tx + TW * ty;
  const int tid = pix + NPIX * tz;           // tz wave-uniform (waves 0-3: tz=0)
  const int b = blockIdx.z;
  const int h0 = blockIdx.y * TH, w0 = blockIdx.x * TW;

  // ---- stage x tile (+halo 5, zero-padded), all 512 threads ----
  for (int i = tid; i < NCELL; i += 512) {
    int r = i / LR_COLS, cc = i - r * LR_COLS;
    int gh = h0 - HALO + r, gw = w0 - HALO + cc;
    bool ok = (gh >= 0) & (gh < HH) & (gw >= 0) & (gw < WW);
    const float* xp = x + (size_t)b * (CIN * HW) + gh * WW + gw;
#pragma unroll
    for (int q = 0; q < 4; ++q) {
      float4 v = make_float4(0.f, 0.f, 0.f, 0.f);
      if (ok) {
        v.x = xp[(q * 4 + 0) * HW];
        v.y = xp[(q * 4 + 1) * HW];
        v.z = xp[(q * 4 + 2) * HW];
        v.w = xp[(q * 4 + 3) * HW];
      }
      xt4[q * NCELL + i] = v;
    }
  }
  __syncthreads();

  const int lbase = (ty + HALO) * LR_COLS + (tx + HALO);
  const float4 xc0 = xt4[0 * NCELL + lbase];
  const float4 xc1 = xt4[1 * NCELL + lbase];
  const float4 xc2 = xt4[2 * NCELL + lbase];
  const float4 xc3 = xt4[3 * NCELL + lbase];
  const f32x2 xcl[8] = { {xc0.x,xc0.y},{xc0.z,xc0.w},{xc1.x,xc1.y},{xc1.z,xc1.w},
                         {xc2.x,xc2.y},{xc2.z,xc2.w},{xc3.x,xc3.y},{xc3.z,xc3.w} };

  // ---- phase 1: each tz computes its half's distinct pairs + 8 sims ----
  float simr[8];
  if (tz == 0) phase1_half<0>(simr, xt4, lbase, xcl);
  else         phase1_half<1>(simr, xt4, lbase, xcl);
#pragma unroll
  for (int gg = 0; gg < 8; ++gg) sims_s[pix][tz * 8 + gg] = simr[gg];
  __syncthreads();

  // ---- selection (redundant in both tz -> no ori broadcast) ----
  float s16[16]; int od[16];
#pragma unroll
  for (int i = 0; i < 16; ++i) { s16[i] = sims_s[pix][i]; od[i] = i; }
#pragma unroll
  for (int p = 0; p < 15; ++p) {
#pragma unroll
    for (int j = 0; j < 15 - p; ++j) {
      float a = s16[j], c = s16[j + 1];
      int oa = od[j], oc = od[j + 1];
      bool sw = a > c;                     // strict -> stable
      s16[j] = sw ? c : a; s16[j + 1] = sw ? a : c;
      od[j] = sw ? oc : oa; od[j + 1] = sw ? oa : oc;
    }
  }
  float best = s16[1] - s16[0]; int ori = od[0];
#pragma unroll
  for (int i = 1; i < 15; ++i) {
    float dd = s16[i + 1] - s16[i];
    if (dd > best) { best = dd; ori = od[i]; }   // strict -> first max
  }
  if (!(best >= 0.001f)) ori = 0;                // INIT_INDEX

  // ---- phase 2: this tz handles o in [tz*16, tz*16+16), packed o-pairs ----
  const int4* crow = (const int4*)&DT.coff[ori * 16];
  int4 cw0 = crow[0], cw1 = crow[1];
  int cellv[16];
  {
    int ws[8] = {cw0.x, cw0.y, cw0.z, cw0.w, cw1.x, cw1.y, cw1.z, cw1.w};
#pragma unroll
    for (int k = 0; k < 8; ++k) {
      cellv[2*k]   = lbase + (int)(int16_t)(ws[k] & 0xffff);
      cellv[2*k+1] = lbase + (int)(int16_t)((unsigned)ws[k] >> 16);
    }
  }

  const int obase = tz * 16;                 // 16 channels -> 8 o-pairs per thread
  f32x2 acc2[8];
#pragma unroll
  for (int k = 0; k < 8; ++k) acc2[k] = f32x2{bias[obase + 2*k], bias[obase + 2*k + 1]};

#pragma unroll
  for (int n = 0; n < 16; ++n) {
    int cell = cellv[n];
    float4 r0 = xt4[0 * NCELL + cell];
    float4 r1 = xt4[1 * NCELL + cell];
    float4 r2 = xt4[2 * NCELL + cell];
    float4 r3 = xt4[3 * NCELL + cell];
    f32x2 pc[8];
    pc[0] = xcl[0] - f32x2{r0.x, r0.y};  pc[1] = xcl[1] - f32x2{r0.z, r0.w};
    pc[2] = xcl[2] - f32x2{r1.x, r1.y};  pc[3] = xcl[3] - f32x2{r1.z, r1.w};
    pc[4] = xcl[4] - f32x2{r2.x, r2.y};  pc[5] = xcl[5] - f32x2{r2.z, r2.w};
    pc[6] = xcl[6] - f32x2{r3.x, r3.y};  pc[7] = xcl[7] - f32x2{r3.z, r3.w};
    const float* wn = wt2 + (n << 9) + (tz << 8);  // wt2[n][o2][c][2], o2 base = tz*8
#pragma unroll
    for (int o2 = 0; o2 < 8; ++o2) {
      const f32x2* wv = (const f32x2*)(wn + (o2 << 5));
      f32x2 a = acc2[o2];
#pragma unroll
      for (int c = 0; c < 16; ++c) {
        float pcv = (c & 1) ? pc[c >> 1].y : pc[c >> 1].x;
        a = __builtin_elementwise_fma(wv[c], splat2(pcv), a);  // v_pk_fma_f32
      }
      acc2[o2] = a;
    }
  }

  const int hh = h0 + ty, wcol = w0 + tx;
  float* op = out + (size_t)b * (COUT * HW) + hh * WW + wcol;
#pragma unroll
  for (int k = 0; k < 8; ++k) {
    op[(obase + 2*k)     * HW] = acc2[k].x;
    op[(obase + 2*k + 1) * HW] = acc2[k].y;
  }
}

extern "C" void kernel_launch(void* const* d_in, const int* in_sizes, int n_in,
                              void* d_out, int out_size, void* d_ws, size_t ws_size,
                              hipStream_t stream) {
  const float* x    = (const float*)d_in[0];
  const float* w    = (const float*)d_in[1];
  const float* bias = (const float*)d_in[2];
  float* out = (float*)d_out;
  float* wt2 = (float*)d_ws;   // 16*16*16*2 f32 = 32 KB scratch

  hipLaunchKernelGGL(transpose_w, dim3(32), dim3(256), 0, stream, w, wt2);

  dim3 grid(WW / TW, HH / TH, NB);
  dim3 block(TW, TH, 2);
  hipLaunchKernelGGL(adapkc_main, grid, block, 0, stream, x, wt2, bias, out);
}

// Round 13
// 86.997 us; speedup vs baseline: 2.1233x; 2.1233x over previous
//
#include <hip/hip_runtime.h>
#include <cstdint>
#include <cstddef>
#include <utility>

#define HH 256
#define WW 256
#define CIN 16
#define COUT 32
#define NB 2
#define TW 32
#define TH 8
#define NPIX (TW*TH)            // 256 pixels/block
#define HALO 5
#define LR_ROWS (TH + 2*HALO)   // 18
#define LR_COLS (TW + 2*HALO)   // 42
#define NCELL (LR_ROWS*LR_COLS) // 756
#define HW (HH*WW)

typedef float f32x2 __attribute__((ext_vector_type(2)));
__device__ __forceinline__ f32x2 splat2(float v) { return f32x2{v, v}; }

// ---------------- compile-time offset tables ----------------
struct alignas(16) Tables {
  int16_t coff[256];    // (g*16+n) -> cell offset dx*LR_COLS+dy (phase 2)
  int16_t pcoff[128];   // dedup'd distinct-pair cell offsets
  uint8_t gmap[256];    // (g*16+n) -> dedup index (phase-1 tree wiring)
  int np;
};

// numpy round-half-to-even for non-negative v (only .0/.5 cases occur)
constexpr int rhe(double v) {
  int f = (int)v;
  double fr = v - (double)f;
  if (fr > 0.5) return f + 1;
  if (fr < 0.5) return f;
  return (f & 1) ? f + 1 : f;
}

constexpr Tables make_tables() {
  Tables t{};
  t.np = 0;
  for (int g = 0; g < 16; ++g) {
    int hp = (g >> 2) + 2;   // rb + gh
    int wp = (g & 3) + 2;    // rb + gw
    int TD[5] = {}, LRr[3] = {};
    for (int j = 0; j < 5; ++j) TD[j] = rhe(j * wp / 2.0) - wp;
    for (int j = 0; j < 3; ++j) LRr[j] = rhe((j + 1) * hp / 2.0) - hp;
    int dxs[16] = {}, dys[16] = {};
    for (int j = 0; j < 5; ++j) { dxs[j]      = -hp;    dys[j]      = TD[j]; }
    for (int j = 0; j < 3; ++j) { dxs[5 + j]  = LRr[j]; dys[5 + j]  =  wp;   }
    for (int j = 0; j < 5; ++j) { dxs[8 + j]  =  hp;    dys[8 + j]  = TD[j]; }
    for (int j = 0; j < 3; ++j) { dxs[13 + j] = LRr[j]; dys[13 + j] = -wp;   }
    for (int n = 0; n < 16; ++n) {
      int co = dxs[n] * LR_COLS + dys[n];
      t.coff[g * 16 + n] = (int16_t)co;
      int d = -1;
      for (int k = 0; k < t.np; ++k)
        if ((int)t.pcoff[k] == co) { d = k; break; }
      if (d < 0) { d = t.np; t.np++; t.pcoff[d] = (int16_t)co; }
      t.gmap[g * 16 + n] = (uint8_t)d;
    }
  }
  return t;
}

constexpr Tables CT = make_tables();
constexpr int NP = CT.np;
static_assert(NP <= 128, "pair table overflow");
static_assert(NP % 4 == 0, "quad remainder");
__device__ const Tables DT = make_tables();   // for runtime-indexed phase-2 reads

// ------- exact transcription of numpy's SIMD f32 exp, 2-wide packed -------
__device__ __forceinline__ f32x2 numpy_expf2(f32x2 v) {
#pragma clang fp contract(off)
  const f32x2 MAGIC = splat2(12582912.0f);         // 1.5 * 2^23
  f32x2 q = __builtin_elementwise_fma(v, splat2(1.442695040888963407359e+00f), MAGIC);
  q = q - MAGIC;                                   // rint(v*log2e), single rounding
  f32x2 r = __builtin_elementwise_fma(q, splat2(-6.93145752e-1f), v);
  r = __builtin_elementwise_fma(q, splat2(-1.42860677e-6f), r);
  f32x2 num = __builtin_elementwise_fma(splat2(5.082762527590693718096e-04f), r,
                                        splat2(6.757896990527504603057e-03f));
  num = __builtin_elementwise_fma(num, r, splat2(5.114512081637298353406e-02f));
  num = __builtin_elementwise_fma(num, r, splat2(2.473615434895520810817e-01f));
  num = __builtin_elementwise_fma(num, r, splat2(7.257664613233124478488e-01f));
  num = __builtin_elementwise_fma(num, r, splat2(9.999999999980870924916e-01f));
  f32x2 den = __builtin_elementwise_fma(splat2(2.159509375685829852307e-02f), r,
                                        splat2(-2.742335390411667452936e-01f));
  den = __builtin_elementwise_fma(den, r, splat2(1.0f));
  f32x2 res;
  res.x = ldexpf(num.x / den.x, (int)q.x);         // IEEE div + exact pow2 scale
  res.y = ldexpf(num.y / den.y, (int)q.y);
  return res;
}

// ---- shared pair-quad body: ONE copy of code (I$-resident), called 28x ----
__device__ __attribute__((noinline))
float4 pair4(const float4* __restrict__ xt4, int c0, int c1, int c2, int c3,
             float4 xc0, float4 xc1, float4 xc2, float4 xc3)
{
#pragma clang fp contract(off)
  const f32x2 xcl[8] = { {xc0.x,xc0.y},{xc0.z,xc0.w},{xc1.x,xc1.y},{xc1.z,xc1.w},
                         {xc2.x,xc2.y},{xc2.z,xc2.w},{xc3.x,xc3.y},{xc3.z,xc3.w} };
  float4 R[4][4];
#pragma unroll
  for (int j = 0; j < 4; ++j) {
    const int cell = (j == 0) ? c0 : (j == 1) ? c1 : (j == 2) ? c2 : c3;
#pragma unroll
    for (int q = 0; q < 4; ++q) R[j][q] = xt4[q * NCELL + cell];
  }
  float mloc[4];
#pragma unroll
  for (int j = 0; j < 4; ++j) {
    // products rounded individually (v_pk_mul pairs 2 IEEE muls/slot)
    f32x2 pr[8];
#pragma unroll
    for (int q = 0; q < 4; ++q) {
      pr[2*q]   = f32x2{R[j][q].x, R[j][q].y} * xcl[2*q];
      pr[2*q+1] = f32x2{R[j][q].z, R[j][q].w} * xcl[2*q+1];
    }
    // sequential channel sum c=0..15 (numpy outer-axis reduce), unfused
    float s = pr[0].x;
    s += pr[0].y; s += pr[1].x; s += pr[1].y;
    s += pr[2].x; s += pr[2].y; s += pr[3].x; s += pr[3].y;
    s += pr[4].x; s += pr[4].y; s += pr[5].x; s += pr[5].y;
    s += pr[6].x; s += pr[6].y; s += pr[7].x; s += pr[7].y;
    mloc[j] = s / 16.0f;                     // exact (pow2)
  }
  f32x2 e0 = numpy_expf2(-f32x2{mloc[0], mloc[1]});
  f32x2 e1 = numpy_expf2(-f32x2{mloc[2], mloc[3]});
  f32x2 d0 = splat2(1.0f) + e0;
  f32x2 d1 = splat2(1.0f) + e1;
  float4 outv;
  outv.x = 1.0f / d0.x; outv.y = 1.0f / d0.y;      // IEEE f32 div
  outv.z = 1.0f / d1.x; outv.w = 1.0f / d1.y;
  return outv;
}

template<size_t... BB>
__device__ __forceinline__ void pairs_call(float* sgv, std::index_sequence<BB...>,
    const float4* xt4, int lbase, float4 xc0, float4 xc1, float4 xc2, float4 xc3)
{
  ((void)([&] {
    float4 r = pair4(xt4,
                     lbase + (int)CT.pcoff[BB*4 + 0], lbase + (int)CT.pcoff[BB*4 + 1],
                     lbase + (int)CT.pcoff[BB*4 + 2], lbase + (int)CT.pcoff[BB*4 + 3],
                     xc0, xc1, xc2, xc3);
    sgv[BB*4 + 0] = r.x; sgv[BB*4 + 1] = r.y;      // static indices -> registers
    sgv[BB*4 + 2] = r.z; sgv[BB*4 + 3] = r.w;
  }()), ...);
}

// ---------- weight transpose: w[o][c][n] -> wt2[n][o/2][c][2] ----------
__global__ void transpose_w(const float* __restrict__ w, float* __restrict__ wt2) {
  int i = blockIdx.x * 256 + threadIdx.x;
  if (i < COUT * CIN * 16) {
    int o = i >> 8, c = (i >> 4) & 15, n = i & 15;
    wt2[(((n * 16 + (o >> 1)) * 16 + c) << 1) + (o & 1)] = w[i];
  }
}

// ---------------- fused main kernel ----------------
__global__ __launch_bounds__(TW * TH)
__attribute__((amdgpu_waves_per_eu(2, 2)))
void adapkc_main(
    const float* __restrict__ x, const float* __restrict__ wt2,
    const float* __restrict__ bias, float* __restrict__ out)
{
#pragma clang fp contract(off)   // numpy never fuses mul+add; keep every rounding
  __shared__ float4 xt4[4 * NCELL];          // 48,384 B
  __shared__ int    scr[NPIX * 17];          // 17,408 B cellv scratch (stride 17: conflict-free)

  const int tx = threadIdx.x, ty = threadIdx.y;
  const int tid = ty * TW + tx;
  const int b = blockIdx.z;
  const int h0 = blockIdx.y * TH, w0 = blockIdx.x * TW;

  // ---- stage x tile (+halo 5, zero-padded) ----
  for (int i = tid; i < NCELL; i += TW * TH) {
    int r = i / LR_COLS, cc = i - r * LR_COLS;
    int gh = h0 - HALO + r, gw = w0 - HALO + cc;
    bool ok = (gh >= 0) & (gh < HH) & (gw >= 0) & (gw < WW);
    const float* xp = x + (size_t)b * (CIN * HW) + gh * WW + gw;
#pragma unroll
    for (int q = 0; q < 4; ++q) {
      float4 v = make_float4(0.f, 0.f, 0.f, 0.f);
      if (ok) {
        v.x = xp[(q * 4 + 0) * HW];
        v.y = xp[(q * 4 + 1) * HW];
        v.z = xp[(q * 4 + 2) * HW];
        v.w = xp[(q * 4 + 3) * HW];
      }
      xt4[q * NCELL + i] = v;
    }
  }
  __syncthreads();

  const int lbase = (ty + HALO) * LR_COLS + (tx + HALO);
  const float4 xc0 = xt4[0 * NCELL + lbase];
  const float4 xc1 = xt4[1 * NCELL + lbase];
  const float4 xc2 = xt4[2 * NCELL + lbase];
  const float4 xc3 = xt4[3 * NCELL + lbase];
  const f32x2 xcl[8] = { {xc0.x,xc0.y},{xc0.z,xc0.w},{xc1.x,xc1.y},{xc1.z,xc1.w},
                         {xc2.x,xc2.y},{xc2.z,xc2.w},{xc3.x,xc3.y},{xc3.z,xc3.w} };

  // ---- phase 1a: 28 calls into ONE pair-quad body ----
  float sgv[NP];
  pairs_call(sgv, std::make_index_sequence<NP / 4>{}, xt4, lbase, xc0, xc1, xc2, xc3);

  // ---- phase 1b: per-group numpy SSE2 pairwise tree (compile-time wiring) ----
  float sim32[16];
#pragma unroll
  for (int g = 0; g < 16; ++g) {
    float A0 = (sgv[CT.gmap[g*16+0]]  + sgv[CT.gmap[g*16+8]])
             + (sgv[CT.gmap[g*16+4]]  + sgv[CT.gmap[g*16+12]]);
    float A1 = (sgv[CT.gmap[g*16+1]]  + sgv[CT.gmap[g*16+9]])
             + (sgv[CT.gmap[g*16+5]]  + sgv[CT.gmap[g*16+13]]);
    float A2 = (sgv[CT.gmap[g*16+2]]  + sgv[CT.gmap[g*16+10]])
             + (sgv[CT.gmap[g*16+6]]  + sgv[CT.gmap[g*16+14]]);
    float A3 = (sgv[CT.gmap[g*16+3]]  + sgv[CT.gmap[g*16+11]])
             + (sgv[CT.gmap[g*16+7]]  + sgv[CT.gmap[g*16+15]]);
    float ssum = (A0 + A2) + (A1 + A3);
    sim32[g] = ssum / 16.0f;                 // exact (pow2)
  }

  // ---- selection: rolled bubble (full 15 comparators x 15 passes == triangular
  //      version bit-exactly: comparators in the sorted tail never swap) ----
  float s16[16]; int od[16];
#pragma unroll
  for (int i = 0; i < 16; ++i) { s16[i] = sim32[i]; od[i] = i; }
#pragma clang loop unroll(disable)
  for (int p = 0; p < 15; ++p) {
#pragma unroll
    for (int j = 0; j < 15; ++j) {
      float a = s16[j], c = s16[j + 1];
      int oa = od[j], oc = od[j + 1];
      bool sw = a > c;                     // strict -> stable
      s16[j] = sw ? c : a; s16[j + 1] = sw ? a : c;
      od[j] = sw ? oc : oa; od[j + 1] = sw ? oa : oc;
    }
  }
  float best = s16[1] - s16[0]; int ori = od[0];
#pragma unroll
  for (int i = 1; i < 15; ++i) {
    float dd = s16[i + 1] - s16[i];
    if (dd > best) { best = dd; ori = od[i]; }   // strict -> first max
  }
  if (!(best >= 0.001f)) ori = 0;                // INIT_INDEX

  // ---- phase 2 (rolled n-loop; cellv staged via LDS scratch) ----
  const int4* crow = (const int4*)&DT.coff[ori * 16];
  int4 cw0 = crow[0], cw1 = crow[1];
  {
    int ws[8] = {cw0.x, cw0.y, cw0.z, cw0.w, cw1.x, cw1.y, cw1.z, cw1.w};
#pragma unroll
    for (int k = 0; k < 8; ++k) {
      scr[tid * 17 + 2*k]     = lbase + (int)(int16_t)(ws[k] & 0xffff);
      scr[tid * 17 + 2*k + 1] = lbase + (int)(int16_t)((unsigned)ws[k] >> 16);
    }
  }

  f32x2 acc2[16];
#pragma unroll
  for (int k = 0; k < 16; ++k) acc2[k] = f32x2{bias[2*k], bias[2*k+1]};

#pragma clang loop unroll(disable)
  for (int n = 0; n < 16; ++n) {
    int cell = scr[tid * 17 + n];            // same-thread write->read: ordered
    float4 r0 = xt4[0 * NCELL + cell];
    float4 r1 = xt4[1 * NCELL + cell];
    float4 r2 = xt4[2 * NCELL + cell];
    float4 r3 = xt4[3 * NCELL + cell];
    f32x2 pc[8];
    pc[0] = xcl[0] - f32x2{r0.x, r0.y};  pc[1] = xcl[1] - f32x2{r0.z, r0.w};
    pc[2] = xcl[2] - f32x2{r1.x, r1.y};  pc[3] = xcl[3] - f32x2{r1.z, r1.w};
    pc[4] = xcl[4] - f32x2{r2.x, r2.y};  pc[5] = xcl[5] - f32x2{r2.z, r2.w};
    pc[6] = xcl[6] - f32x2{r3.x, r3.y};  pc[7] = xcl[7] - f32x2{r3.z, r3.w};
    const float* wn = wt2 + (n << 9);        // uniform (n is loop-uniform)
#pragma unroll
    for (int o2 = 0; o2 < 16; ++o2) {
      const f32x2* wv = (const f32x2*)(wn + (o2 << 5));
      f32x2 a = acc2[o2];
#pragma unroll
      for (int c = 0; c < 16; ++c) {
        float pcv = (c & 1) ? pc[c >> 1].y : pc[c >> 1].x;
        a = __builtin_elementwise_fma(wv[c], splat2(pcv), a);  // v_pk_fma_f32
      }
      acc2[o2] = a;
    }
  }

  const int hh = h0 + ty, wcol = w0 + tx;
  float* op = out + (size_t)b * (COUT * HW) + hh * WW + wcol;
#pragma unroll
  for (int k = 0; k < 16; ++k) {
    op[(2*k)     * HW] = acc2[k].x;
    op[(2*k + 1) * HW] = acc2[k].y;
  }
}

extern "C" void kernel_launch(void* const* d_in, const int* in_sizes, int n_in,
                              void* d_out, int out_size, void* d_ws, size_t ws_size,
                              hipStream_t stream) {
  const float* x    = (const float*)d_in[0];
  const float* w    = (const float*)d_in[1];
  const float* bias = (const float*)d_in[2];
  float* out = (float*)d_out;
  float* wt2 = (float*)d_ws;   // 16*16*16*2 f32 = 32 KB scratch

  hipLaunchKernelGGL(transpose_w, dim3(32), dim3(256), 0, stream, w, wt2);

  dim3 grid(WW / TW, HH / TH, NB);
  dim3 block(TW, TH, 1);
  hipLaunchKernelGGL(adapkc_main, grid, block, 0, stream, x, wt2, bias, out);
}

// Round 14
// 63.228 us; speedup vs baseline: 2.9216x; 1.3759x over previous
//
#include <hip/hip_runtime.h>
#include <cstdint>
#include <cstddef>
#include <utility>

#define HH 256
#define WW 256
#define CIN 16
#define COUT 32
#define NB 2
#define TW 32
#define TH 8
#define NPIX (TW*TH)            // 256 pixels/block
#define HALO 5
#define LR_ROWS (TH + 2*HALO)   // 18
#define LR_COLS (TW + 2*HALO)   // 42
#define NCELL (LR_ROWS*LR_COLS) // 756
#define HW (HH*WW)

typedef float f32x2 __attribute__((ext_vector_type(2)));
typedef float f32x4 __attribute__((ext_vector_type(4)));
typedef short bf16x8 __attribute__((ext_vector_type(8)));
__device__ __forceinline__ f32x2 splat2(float v) { return f32x2{v, v}; }

// RNE f32->bf16 (bit trick == HW cvt for finite values)
__device__ __forceinline__ unsigned short f2bf(float f) {
  unsigned u = __float_as_uint(f);
  return (unsigned short)((u + 0x7fffu + ((u >> 16) & 1u)) >> 16);
}

// ---------------- compile-time offset tables ----------------
struct alignas(16) Tables {
  int16_t coff[256];    // (g*16+n) -> cell offset dx*LR_COLS+dy (phase 2)
  int16_t pcoff[128];   // dedup'd distinct-pair cell offsets
  uint8_t gmap[256];    // (g*16+n) -> dedup index (phase-1 tree wiring)
  int np;
};

// numpy round-half-to-even for non-negative v (only .0/.5 cases occur)
constexpr int rhe(double v) {
  int f = (int)v;
  double fr = v - (double)f;
  if (fr > 0.5) return f + 1;
  if (fr < 0.5) return f;
  return (f & 1) ? f + 1 : f;
}

constexpr Tables make_tables() {
  Tables t{};
  t.np = 0;
  for (int g = 0; g < 16; ++g) {
    int hp = (g >> 2) + 2;   // rb + gh
    int wp = (g & 3) + 2;    // rb + gw
    int TD[5] = {}, LRr[3] = {};
    for (int j = 0; j < 5; ++j) TD[j] = rhe(j * wp / 2.0) - wp;
    for (int j = 0; j < 3; ++j) LRr[j] = rhe((j + 1) * hp / 2.0) - hp;
    int dxs[16] = {}, dys[16] = {};
    for (int j = 0; j < 5; ++j) { dxs[j]      = -hp;    dys[j]      = TD[j]; }
    for (int j = 0; j < 3; ++j) { dxs[5 + j]  = LRr[j]; dys[5 + j]  =  wp;   }
    for (int j = 0; j < 5; ++j) { dxs[8 + j]  =  hp;    dys[8 + j]  = TD[j]; }
    for (int j = 0; j < 3; ++j) { dxs[13 + j] = LRr[j]; dys[13 + j] = -wp;   }
    for (int n = 0; n < 16; ++n) {
      int co = dxs[n] * LR_COLS + dys[n];
      t.coff[g * 16 + n] = (int16_t)co;
      int d = -1;
      for (int k = 0; k < t.np; ++k)
        if ((int)t.pcoff[k] == co) { d = k; break; }
      if (d < 0) { d = t.np; t.np++; t.pcoff[d] = (int16_t)co; }
      t.gmap[g * 16 + n] = (uint8_t)d;
    }
  }
  return t;
}

constexpr Tables CT = make_tables();
constexpr int NP = CT.np;
static_assert(NP <= 128, "pair table overflow");
static_assert(NP % 4 == 0, "quad remainder");
__device__ const Tables DT = make_tables();   // for runtime-indexed phase-2 reads

// ------- exact transcription of numpy's SIMD f32 exp, 2-wide packed -------
__device__ __forceinline__ f32x2 numpy_expf2(f32x2 v) {
#pragma clang fp contract(off)
  const f32x2 MAGIC = splat2(12582912.0f);         // 1.5 * 2^23
  f32x2 q = __builtin_elementwise_fma(v, splat2(1.442695040888963407359e+00f), MAGIC);
  q = q - MAGIC;                                   // rint(v*log2e), single rounding
  f32x2 r = __builtin_elementwise_fma(q, splat2(-6.93145752e-1f), v);
  r = __builtin_elementwise_fma(q, splat2(-1.42860677e-6f), r);
  f32x2 num = __builtin_elementwise_fma(splat2(5.082762527590693718096e-04f), r,
                                        splat2(6.757896990527504603057e-03f));
  num = __builtin_elementwise_fma(num, r, splat2(5.114512081637298353406e-02f));
  num = __builtin_elementwise_fma(num, r, splat2(2.473615434895520810817e-01f));
  num = __builtin_elementwise_fma(num, r, splat2(7.257664613233124478488e-01f));
  num = __builtin_elementwise_fma(num, r, splat2(9.999999999980870924916e-01f));
  f32x2 den = __builtin_elementwise_fma(splat2(2.159509375685829852307e-02f), r,
                                        splat2(-2.742335390411667452936e-01f));
  den = __builtin_elementwise_fma(den, r, splat2(1.0f));
  f32x2 res;
  res.x = ldexpf(num.x / den.x, (int)q.x);         // IEEE div + exact pow2 scale
  res.y = ldexpf(num.y / den.y, (int)q.y);
  return res;
}

// ---- shared pair-quad body: ONE copy of code (I$-resident), called 28x ----
__device__ __attribute__((noinline))
float4 pair4(const float4* __restrict__ xt4, int c0, int c1, int c2, int c3,
             float4 xc0, float4 xc1, float4 xc2, float4 xc3)
{
#pragma clang fp contract(off)
  const f32x2 xcl[8] = { {xc0.x,xc0.y},{xc0.z,xc0.w},{xc1.x,xc1.y},{xc1.z,xc1.w},
                         {xc2.x,xc2.y},{xc2.z,xc2.w},{xc3.x,xc3.y},{xc3.z,xc3.w} };
  float4 R[4][4];
#pragma unroll
  for (int j = 0; j < 4; ++j) {
    const int cell = (j == 0) ? c0 : (j == 1) ? c1 : (j == 2) ? c2 : c3;
#pragma unroll
    for (int q = 0; q < 4; ++q) R[j][q] = xt4[q * NCELL + cell];
  }
  float mloc[4];
#pragma unroll
  for (int j = 0; j < 4; ++j) {
    f32x2 pr[8];
#pragma unroll
    for (int q = 0; q < 4; ++q) {
      pr[2*q]   = f32x2{R[j][q].x, R[j][q].y} * xcl[2*q];
      pr[2*q+1] = f32x2{R[j][q].z, R[j][q].w} * xcl[2*q+1];
    }
    // sequential channel sum c=0..15 (numpy outer-axis reduce), unfused
    float s = pr[0].x;
    s += pr[0].y; s += pr[1].x; s += pr[1].y;
    s += pr[2].x; s += pr[2].y; s += pr[3].x; s += pr[3].y;
    s += pr[4].x; s += pr[4].y; s += pr[5].x; s += pr[5].y;
    s += pr[6].x; s += pr[6].y; s += pr[7].x; s += pr[7].y;
    mloc[j] = s / 16.0f;                     // exact (pow2)
  }
  f32x2 e0 = numpy_expf2(-f32x2{mloc[0], mloc[1]});
  f32x2 e1 = numpy_expf2(-f32x2{mloc[2], mloc[3]});
  f32x2 d0 = splat2(1.0f) + e0;
  f32x2 d1 = splat2(1.0f) + e1;
  float4 outv;
  outv.x = 1.0f / d0.x; outv.y = 1.0f / d0.y;      // IEEE f32 div
  outv.z = 1.0f / d1.x; outv.w = 1.0f / d1.y;
  return outv;
}

template<size_t... BB>
__device__ __forceinline__ void pairs_call(float* sgv, std::index_sequence<BB...>,
    const float4* xt4, int lbase, float4 xc0, float4 xc1, float4 xc2, float4 xc3)
{
  ((void)([&] {
    float4 r = pair4(xt4,
                     lbase + (int)CT.pcoff[BB*4 + 0], lbase + (int)CT.pcoff[BB*4 + 1],
                     lbase + (int)CT.pcoff[BB*4 + 2], lbase + (int)CT.pcoff[BB*4 + 3],
                     xc0, xc1, xc2, xc3);
    sgv[BB*4 + 0] = r.x; sgv[BB*4 + 1] = r.y;      // static indices -> registers
    sgv[BB*4 + 2] = r.z; sgv[BB*4 + 3] = r.w;
  }()), ...);
}

// -------- A-operand pack: w[o][c][n] -> per-lane MFMA fragment order --------
// wsA[((m*8+s)*64 + lane)*8 + j] = bf16(w[o=m*16+(lane&15)][c=(h&1)*8+j][n=2s+(h>>1)])
__global__ void pack_A(const float* __restrict__ w, unsigned short* __restrict__ wsA) {
  int i = blockIdx.x * 256 + threadIdx.x;
  if (i < 2 * 8 * 64 * 8) {
    int m = i >> 12, s = (i >> 9) & 7, l = (i >> 3) & 63, j = i & 7;
    int h = l >> 4, col = l & 15;
    int o = m * 16 + col;
    int n = 2 * s + (h >> 1);
    int c = (h & 1) * 8 + j;
    wsA[i] = f2bf(w[(o * CIN + c) * 16 + n]);
  }
}

// ---------------- fused main kernel ----------------
__global__ __launch_bounds__(TW * TH)
__attribute__((amdgpu_waves_per_eu(2, 2)))
void adapkc_main(
    const float* __restrict__ x, const unsigned short* __restrict__ wsA,
    const float* __restrict__ bias, float* __restrict__ out)
{
#pragma clang fp contract(off)   // numpy never fuses mul+add; keep every rounding
  __shared__ float4 xt4[4 * NCELL];          // 48,384 B
  __shared__ int    ori_s[NPIX];             //  1,024 B

  const int tx = threadIdx.x, ty = threadIdx.y;
  const int tid = ty * TW + tx;
  const int b = blockIdx.z;
  const int h0 = blockIdx.y * TH, w0 = blockIdx.x * TW;

  // ---- stage x tile (+halo 5, zero-padded) ----
  for (int i = tid; i < NCELL; i += TW * TH) {
    int r = i / LR_COLS, cc = i - r * LR_COLS;
    int gh = h0 - HALO + r, gw = w0 - HALO + cc;
    bool ok = (gh >= 0) & (gh < HH) & (gw >= 0) & (gw < WW);
    const float* xp = x + (size_t)b * (CIN * HW) + gh * WW + gw;
#pragma unroll
    for (int q = 0; q < 4; ++q) {
      float4 v = make_float4(0.f, 0.f, 0.f, 0.f);
      if (ok) {
        v.x = xp[(q * 4 + 0) * HW];
        v.y = xp[(q * 4 + 1) * HW];
        v.z = xp[(q * 4 + 2) * HW];
        v.w = xp[(q * 4 + 3) * HW];
      }
      xt4[q * NCELL + i] = v;
    }
  }
  __syncthreads();

  const int lbase = (ty + HALO) * LR_COLS + (tx + HALO);
  const float4 xc0 = xt4[0 * NCELL + lbase];
  const float4 xc1 = xt4[1 * NCELL + lbase];
  const float4 xc2 = xt4[2 * NCELL + lbase];
  const float4 xc3 = xt4[3 * NCELL + lbase];

  // ---- phase 1a: 28 calls into ONE pair-quad body ----
  float sgv[NP];
  pairs_call(sgv, std::make_index_sequence<NP / 4>{}, xt4, lbase, xc0, xc1, xc2, xc3);

  // ---- phase 1b: per-group numpy SSE2 pairwise tree (compile-time wiring) ----
  float sim32[16];
#pragma unroll
  for (int g = 0; g < 16; ++g) {
    float A0 = (sgv[CT.gmap[g*16+0]]  + sgv[CT.gmap[g*16+8]])
             + (sgv[CT.gmap[g*16+4]]  + sgv[CT.gmap[g*16+12]]);
    float A1 = (sgv[CT.gmap[g*16+1]]  + sgv[CT.gmap[g*16+9]])
             + (sgv[CT.gmap[g*16+5]]  + sgv[CT.gmap[g*16+13]]);
    float A2 = (sgv[CT.gmap[g*16+2]]  + sgv[CT.gmap[g*16+10]])
             + (sgv[CT.gmap[g*16+6]]  + sgv[CT.gmap[g*16+14]]);
    float A3 = (sgv[CT.gmap[g*16+3]]  + sgv[CT.gmap[g*16+11]])
             + (sgv[CT.gmap[g*16+7]]  + sgv[CT.gmap[g*16+15]]);
    float ssum = (A0 + A2) + (A1 + A3);
    sim32[g] = ssum / 16.0f;                 // exact (pow2)
  }

  // ---- selection: rolled bubble (bit-exact vs triangular version) ----
  float s16[16]; int od[16];
#pragma unroll
  for (int i = 0; i < 16; ++i) { s16[i] = sim32[i]; od[i] = i; }
#pragma clang loop unroll(disable)
  for (int p = 0; p < 15; ++p) {
#pragma unroll
    for (int j = 0; j < 15; ++j) {
      float a = s16[j], c = s16[j + 1];
      int oa = od[j], oc = od[j + 1];
      bool sw = a > c;                     // strict -> stable
      s16[j] = sw ? c : a; s16[j + 1] = sw ? a : c;
      od[j] = sw ? oc : oa; od[j + 1] = sw ? oa : oc;
    }
  }
  float best = s16[1] - s16[0]; int ori = od[0];
#pragma unroll
  for (int i = 1; i < 15; ++i) {
    float dd = s16[i + 1] - s16[i];
    if (dd > best) { best = dd; ori = od[i]; }   // strict -> first max
  }
  if (!(best >= 0.001f)) ori = 0;                // INIT_INDEX

  ori_s[tid] = ori;
  __syncthreads();

  // ---- phase 2: bf16 MFMA.  D[o][pix] = sum_k W[o,k] P[k,pix], K=256 ----
  const int lane  = tid & 63;
  const int wavei = tid >> 6;
  const int hq  = lane >> 4;         // quarter-group
  const int col = lane & 15;         // D column = pixel-within-group
  const int q0  = (hq & 1) * 2;      // this lane's channel-half chunks

  // A fragments (weights), per-lane order prepacked by pack_A
  bf16x8 afr[2][8];
#pragma unroll
  for (int m = 0; m < 2; ++m)
#pragma unroll
    for (int s = 0; s < 8; ++s)
      afr[m][s] = *(const bf16x8*)(wsA + (((m * 8 + s) * 64 + lane) << 3));

  float bv[2][4];
#pragma unroll
  for (int m = 0; m < 2; ++m)
#pragma unroll
    for (int r = 0; r < 4; ++r) bv[m][r] = bias[m * 16 + hq * 4 + r];

  f32x4 acc[2][4];
#pragma unroll
  for (int m = 0; m < 2; ++m)
#pragma unroll
    for (int t = 0; t < 4; ++t)
      acc[m][t] = f32x4{bv[m][0], bv[m][1], bv[m][2], bv[m][3]};

#pragma unroll
  for (int t = 0; t < 4; ++t) {
    const int p  = wavei * 64 + t * 16 + col;   // pixel this lane serves
    const int py = p >> 5, px = p & 31;
    const int lb = (py + HALO) * LR_COLS + (px + HALO);
    const int orip = ori_s[p];
    const int4* cr = (const int4*)&DT.coff[orip * 16];
    int4 cA = cr[0], cB = cr[1];
    int dw[8] = {cA.x, cA.y, cA.z, cA.w, cB.x, cB.y, cB.z, cB.w};
    const float4 xca = xt4[q0 * NCELL + lb];
    const float4 xcb = xt4[(q0 + 1) * NCELL + lb];
#pragma unroll
    for (int s = 0; s < 8; ++s) {
      int pk = dw[s];
      int off16 = (hq >= 2) ? (int)(int16_t)((unsigned)pk >> 16)
                            : (int)(int16_t)(pk & 0xffff);
      int cell = lb + off16;
      float4 ra = xt4[q0 * NCELL + cell];
      float4 rb = xt4[(q0 + 1) * NCELL + cell];
      bf16x8 bfr;
      bfr[0] = (short)f2bf(xca.x - ra.x);
      bfr[1] = (short)f2bf(xca.y - ra.y);
      bfr[2] = (short)f2bf(xca.z - ra.z);
      bfr[3] = (short)f2bf(xca.w - ra.w);
      bfr[4] = (short)f2bf(xcb.x - rb.x);
      bfr[5] = (short)f2bf(xcb.y - rb.y);
      bfr[6] = (short)f2bf(xcb.z - rb.z);
      bfr[7] = (short)f2bf(xcb.w - rb.w);
      acc[0][t] = __builtin_amdgcn_mfma_f32_16x16x32_bf16(afr[0][s], bfr, acc[0][t], 0, 0, 0);
      acc[1][t] = __builtin_amdgcn_mfma_f32_16x16x32_bf16(afr[1][s], bfr, acc[1][t], 0, 0, 0);
    }
  }

  // ---- store: D row = o = m*16 + hq*4 + r; D col = pixel p(t, col) ----
#pragma unroll
  for (int t = 0; t < 4; ++t) {
    const int p  = wavei * 64 + t * 16 + col;
    const int hh = h0 + (p >> 5), ww = w0 + (p & 31);
    float* op = out + (size_t)b * (COUT * HW) + hh * WW + ww;
#pragma unroll
    for (int m = 0; m < 2; ++m)
#pragma unroll
      for (int r = 0; r < 4; ++r)
        op[(m * 16 + hq * 4 + r) * HW] = acc[m][t][r];
  }
}

extern "C" void kernel_launch(void* const* d_in, const int* in_sizes, int n_in,
                              void* d_out, int out_size, void* d_ws, size_t ws_size,
                              hipStream_t stream) {
  const float* x    = (const float*)d_in[0];
  const float* w    = (const float*)d_in[1];
  const float* bias = (const float*)d_in[2];
  float* out = (float*)d_out;
  unsigned short* wsA = (unsigned short*)d_ws;   // 8192 bf16 = 16 KB scratch

  hipLaunchKernelGGL(pack_A, dim3(32), dim3(256), 0, stream, w, wsA);

  dim3 grid(WW / TW, HH / TH, NB);
  dim3 block(TW, TH, 1);
  hipLaunchKernelGGL(adapkc_main, grid, block, 0, stream, x, wsA, bias, out);
}